// Round 3
// baseline (2054.239 us; speedup 1.0000x reference)
//
#include <hip/hip_runtime.h>

// GNN node embedding (GINEConv x5), fp32, MI355X gfx950.
// N=50000 nodes, E=800000 edges, D=64, X_DIM=92, EA_DIM=50, L=5.
//
// Structure per call:
//   k_prep: transpose atom_W, mlp_W1, mlp_W2 into ws
//   k_atom: h = x @ atom_W + b              (lane=node, uniform-weight s_loads)
//   CSR build (once): k_deg -> k_scan_a -> k_scan_b -> k_fill -> k_scatter
//   per layer: k_aggr (wave-per-dst-node pull, registers, no atomics; fused z)
//              -> k_mlp (t over z in-place) -> k_stats -> k_apply

#define NN 50000
#define NE 800000
#define D 64
#define NL 5
#define XD 92
#define EAD 50
#define BN_EPS 1e-5f
#define NBLK ((NN + 255) / 256)   // 196 scan blocks

// ---------------- prep: transpose weights ----------------
__global__ void k_prep(const float* __restrict__ atomW, const float* __restrict__ W1,
                       const float* __restrict__ W2, float* __restrict__ atomWt,
                       float* __restrict__ W1t, float* __restrict__ W2t) {
  int tid = blockIdx.x * blockDim.x + threadIdx.x;
  int nt = gridDim.x * blockDim.x;
  for (int i = tid; i < XD * D; i += nt) {
    int k = i / D, d = i % D;
    atomWt[d * XD + k] = atomW[i];
  }
  for (int i = tid; i < NL * D * D; i += nt) {
    int l = i / (D * D), r = i % (D * D);
    int k = r / D, d = r % D;
    W1t[(l * D + d) * D + k] = W1[i];
    W2t[(l * D + d) * D + k] = W2[i];
  }
}

// ---------------- atom encoder: h = x @ atom_W + b ----------------
__global__ __launch_bounds__(256) void k_atom(const float* __restrict__ x,
    const float* __restrict__ Wt, const float* __restrict__ b,
    float* __restrict__ h) {
  int n = blockIdx.x * blockDim.x + threadIdx.x;
  if (n >= NN) return;
  const float* xp = x + (size_t)n * XD;
  float xr[XD];
#pragma unroll
  for (int k = 0; k < XD; k += 4) {  // 92*4B = 368B rows, 16B-aligned
    float4 v = *reinterpret_cast<const float4*>(xp + k);
    xr[k] = v.x; xr[k + 1] = v.y; xr[k + 2] = v.z; xr[k + 3] = v.w;
  }
  float hr[D];
#pragma unroll
  for (int d = 0; d < D; ++d) {
    const float* wr = Wt + d * XD;  // uniform address -> s_loads
    float a0 = 0.f, a1 = 0.f, a2 = 0.f, a3 = 0.f;
#pragma unroll
    for (int k = 0; k < XD; k += 4) {
      a0 = fmaf(xr[k + 0], wr[k + 0], a0);
      a1 = fmaf(xr[k + 1], wr[k + 1], a1);
      a2 = fmaf(xr[k + 2], wr[k + 2], a2);
      a3 = fmaf(xr[k + 3], wr[k + 3], a3);
    }
    hr[d] = (a0 + a1) + (a2 + a3) + b[d];
  }
  float* hp = h + (size_t)n * D;
#pragma unroll
  for (int d = 0; d < D; d += 4)
    *reinterpret_cast<float4*>(hp + d) = make_float4(hr[d], hr[d+1], hr[d+2], hr[d+3]);
}

// ---------------- CSR build ----------------
__global__ __launch_bounds__(256) void k_deg(const int* __restrict__ ei,
                                             int* __restrict__ deg) {
  int e = blockIdx.x * blockDim.x + threadIdx.x;
  if (e < NE) atomicAdd(&deg[ei[NE + e]], 1);
}

// block-local inclusive scan (Hillis-Steele, 256 wide) -> exclusive out + block sums
__global__ __launch_bounds__(256) void k_scan_a(const int* __restrict__ deg,
    int* __restrict__ lps, int* __restrict__ bsum) {
  __shared__ int s[256];
  int t = threadIdx.x;
  int i = blockIdx.x * 256 + t;
  int v = (i < NN) ? deg[i] : 0;
  s[t] = v;
  __syncthreads();
#pragma unroll
  for (int off = 1; off < 256; off <<= 1) {
    int xv = (t >= off) ? s[t - off] : 0;
    __syncthreads();
    s[t] += xv;
    __syncthreads();
  }
  if (i < NN) lps[i] = s[t] - v;         // exclusive
  if (t == 255) bsum[blockIdx.x] = s[255];
}

__global__ __launch_bounds__(256) void k_scan_b(const int* __restrict__ bsum,
                                                int* __restrict__ bpre) {
  __shared__ int s[256];
  int t = threadIdx.x;
  int v = (t < NBLK) ? bsum[t] : 0;
  s[t] = v;
  __syncthreads();
#pragma unroll
  for (int off = 1; off < 256; off <<= 1) {
    int xv = (t >= off) ? s[t - off] : 0;
    __syncthreads();
    s[t] += xv;
    __syncthreads();
  }
  bpre[t] = s[t] - v;
}

__global__ __launch_bounds__(256) void k_fill(const int* __restrict__ lps,
    const int* __restrict__ bpre, int* __restrict__ rowptr,
    int* __restrict__ cursor) {
  int i = blockIdx.x * blockDim.x + threadIdx.x;
  if (i < NN) {
    int v = lps[i] + bpre[i >> 8];
    rowptr[i] = v;
    cursor[i] = v;
  }
  if (i == 0) rowptr[NN] = NE;
}

__global__ __launch_bounds__(256) void k_scatter(const int* __restrict__ ei,
    int* __restrict__ cursor, int* __restrict__ esrc, int* __restrict__ eidl) {
  int e = blockIdx.x * blockDim.x + threadIdx.x;
  if (e >= NE) return;
  int dst = ei[NE + e];
  int p = atomicAdd(&cursor[dst], 1);
  esrc[p] = ei[e];
  eidl[p] = e;
}

// ---------------- pull aggregation + fused z = (1+eps)h + agg ----------------
// wave-per-dst-node: lane = feature dim d. Node id / edge list / ea rows are
// wave-uniform (readfirstlane-forced -> SGPR addressing); h[src] row is one
// coalesced 256B vector load; accumulate in registers (no atomics).
// grid 3125 -> 12500 waves -> 4 nodes/wave: amortizes the 50-load wc[] preload.
__global__ __launch_bounds__(256) void k_aggr(const float* __restrict__ h,
    const float* __restrict__ ea, const float* __restrict__ eW,
    const float* __restrict__ eb, const int* __restrict__ rowptr,
    const int* __restrict__ esrc, const int* __restrict__ eidl,
    const float* __restrict__ eps, int layer, float* __restrict__ z) {
  int lane = threadIdx.x & 63;
  int wid = __builtin_amdgcn_readfirstlane(blockIdx.x * 4 + (threadIdx.x >> 6));
  int nw = gridDim.x * 4;
  const float* Wl = eW + (size_t)layer * EAD * D;
  float wc[EAD];
#pragma unroll
  for (int k = 0; k < EAD; ++k) wc[k] = Wl[k * D + lane];  // coalesced column
  float bd = eb[layer * D + lane];
  float ope = 1.f + eps[layer];
  for (int n = wid; n < NN; n += nw) {
    int beg = __builtin_amdgcn_readfirstlane(rowptr[n]);
    int end = __builtin_amdgcn_readfirstlane(rowptr[n + 1]);
    float acc = 0.f;
    for (int idx = beg; idx < end; ++idx) {
      int e   = __builtin_amdgcn_readfirstlane(eidl[idx]);
      int src = __builtin_amdgcn_readfirstlane(esrc[idx]);
      // ea row: 200B, 8B-aligned -> 25 uniform float2 loads
      const float2* ep2 = reinterpret_cast<const float2*>(ea + (size_t)e * EAD);
      float a0 = 0.f, a1 = 0.f, a2 = 0.f, a3 = 0.f;
#pragma unroll
      for (int k2 = 0; k2 < 24; k2 += 2) {
        float2 p0 = ep2[k2];
        float2 p1 = ep2[k2 + 1];
        a0 = fmaf(p0.x, wc[2 * k2 + 0], a0);
        a1 = fmaf(p0.y, wc[2 * k2 + 1], a1);
        a2 = fmaf(p1.x, wc[2 * k2 + 2], a2);
        a3 = fmaf(p1.y, wc[2 * k2 + 3], a3);
      }
      float2 pt = ep2[24];
      a0 = fmaf(pt.x, wc[48], a0);
      a1 = fmaf(pt.y, wc[49], a1);
      float lin = (a0 + a1) + (a2 + a3) + bd;
      acc += fmaxf(h[(size_t)src * D + lane] + lin, 0.f);
    }
    z[(size_t)n * D + lane] = fmaf(ope, h[(size_t)n * D + lane], acc);
  }
}

// ---------------- node MLP: t = relu(z@W1+b1)@W2+b2, in-place over z ----------------
__global__ __launch_bounds__(256) void k_mlp(const float* __restrict__ W1t,
    const float* __restrict__ b1, const float* __restrict__ W2t,
    const float* __restrict__ b2, int layer, float* __restrict__ z) {
  int n = blockIdx.x * blockDim.x + threadIdx.x;
  if (n >= NN) return;
  float* zp = z + (size_t)n * D;
  float zr[D];
#pragma unroll
  for (int k = 0; k < D; k += 4) {
    float4 v = *reinterpret_cast<const float4*>(zp + k);
    zr[k] = v.x; zr[k+1] = v.y; zr[k+2] = v.z; zr[k+3] = v.w;
  }
  const float* W1l = W1t + (size_t)layer * D * D;
  const float* b1l = b1 + layer * D;
  float y[D];
#pragma unroll
  for (int d = 0; d < D; ++d) {
    const float* wr = W1l + d * D;  // uniform
    float a0 = 0.f, a1 = 0.f, a2 = 0.f, a3 = 0.f;
#pragma unroll
    for (int k = 0; k < D; k += 4) {
      a0 = fmaf(zr[k + 0], wr[k + 0], a0);
      a1 = fmaf(zr[k + 1], wr[k + 1], a1);
      a2 = fmaf(zr[k + 2], wr[k + 2], a2);
      a3 = fmaf(zr[k + 3], wr[k + 3], a3);
    }
    y[d] = fmaxf((a0 + a1) + (a2 + a3) + b1l[d], 0.f);
  }
  const float* W2l = W2t + (size_t)layer * D * D;
  const float* b2l = b2 + layer * D;
#pragma unroll
  for (int d = 0; d < D; ++d) {
    const float* wr = W2l + d * D;  // uniform
    float a0 = 0.f, a1 = 0.f, a2 = 0.f, a3 = 0.f;
#pragma unroll
    for (int k = 0; k < D; k += 4) {
      a0 = fmaf(y[k + 0], wr[k + 0], a0);
      a1 = fmaf(y[k + 1], wr[k + 1], a1);
      a2 = fmaf(y[k + 2], wr[k + 2], a2);
      a3 = fmaf(y[k + 3], wr[k + 3], a3);
    }
    zr[d] = (a0 + a1) + (a2 + a3) + b2l[d];
  }
#pragma unroll
  for (int d = 0; d < D; d += 4)
    *reinterpret_cast<float4*>(zp + d) = make_float4(zr[d], zr[d+1], zr[d+2], zr[d+3]);
}

// ---------------- BN stats: per-feature sum / sumsq ----------------
__global__ __launch_bounds__(256) void k_stats(const float* __restrict__ t,
                                               float* __restrict__ stats) {
  int lane = threadIdx.x & 63;
  int w = threadIdx.x >> 6;
  int gw = blockIdx.x * 4 + w;
  int nw = gridDim.x * 4;
  float s = 0.f, q = 0.f;
  for (int n = gw; n < NN; n += nw) {
    float v = t[(size_t)n * D + lane];
    s += v;
    q = fmaf(v, v, q);
  }
  __shared__ float ls[8][64];
  ls[w][lane] = s;
  ls[4 + w][lane] = q;
  __syncthreads();
  if (threadIdx.x < D) {
    float S = ls[0][lane] + ls[1][lane] + ls[2][lane] + ls[3][lane];
    float Q = ls[4][lane] + ls[5][lane] + ls[6][lane] + ls[7][lane];
    unsafeAtomicAdd(&stats[lane], S);
    unsafeAtomicAdd(&stats[D + lane], Q);
  }
}

// ---------------- BN apply (+relu except last layer) ----------------
__global__ __launch_bounds__(256) void k_apply(const float* __restrict__ t,
    const float* __restrict__ stats, const float* __restrict__ gamma,
    const float* __restrict__ beta, int layer, int last, float* __restrict__ o) {
  const float inv = 1.f / (float)NN;
  int i = blockIdx.x * blockDim.x + threadIdx.x;
  int nt = gridDim.x * blockDim.x;
  for (; i < NN * D / 4; i += nt) {
    int d0 = (i & 15) * 4;
    float4 v = reinterpret_cast<const float4*>(t)[i];
    float vv[4] = {v.x, v.y, v.z, v.w};
    float r[4];
#pragma unroll
    for (int c = 0; c < 4; ++c) {
      int d = d0 + c;
      float mu = stats[d] * inv;
      float var = fmaf(-mu, mu, stats[D + d] * inv);
      float sc = gamma[layer * D + d] / sqrtf(var + BN_EPS);
      float val = fmaf(vv[c] - mu, sc, beta[layer * D + d]);
      r[c] = last ? val : fmaxf(val, 0.f);
    }
    reinterpret_cast<float4*>(o)[i] = make_float4(r[0], r[1], r[2], r[3]);
  }
}

extern "C" void kernel_launch(void* const* d_in, const int* in_sizes, int n_in,
                              void* d_out, int out_size, void* d_ws, size_t ws_size,
                              hipStream_t stream) {
  const float* x     = (const float*)d_in[0];
  const int*   ei    = (const int*)d_in[1];
  const float* ea    = (const float*)d_in[2];
  const float* atomW = (const float*)d_in[3];
  const float* atomB = (const float*)d_in[4];
  const float* eW    = (const float*)d_in[5];
  const float* eb    = (const float*)d_in[6];
  const float* W1    = (const float*)d_in[7];
  const float* b1    = (const float*)d_in[8];
  const float* W2    = (const float*)d_in[9];
  const float* b2    = (const float*)d_in[10];
  const float* eps   = (const float*)d_in[11];
  const float* gamma = (const float*)d_in[12];
  const float* beta  = (const float*)d_in[13];
  float* out = (float*)d_out;

  char* ws = (char*)d_ws;
  float* h      = (float*)ws;                                // NN*D
  float* z      = h + (size_t)NN * D;                        // NN*D (z, then t)
  float* stats  = z + (size_t)NN * D;                        // 2*D
  float* atomWt = stats + 2 * D;                             // D*XD
  float* W1t    = atomWt + D * XD;                           // NL*D*D
  float* W2t    = W1t + NL * D * D;                          // NL*D*D
  int*   deg    = (int*)(W2t + NL * D * D);                  // NN
  int*   lps    = deg + NN;                                  // NN
  int*   rowptr = lps + NN;                                  // NN+1
  int*   cursor = rowptr + NN + 1;                           // NN
  int*   bsum   = cursor + NN;                               // 256
  int*   bpre   = bsum + 256;                                // 256
  int*   esrc   = bpre + 256;                                // NE
  int*   eidl   = esrc + NE;                                 // NE
  // total ws use ~= 33 MB

  // weights + atom encoder
  k_prep<<<64, 256, 0, stream>>>(atomW, W1, W2, atomWt, W1t, W2t);
  k_atom<<<(NN + 255) / 256, 256, 0, stream>>>(x, atomWt, atomB, h);

  // CSR build (edge_index fixed per call, but rebuilt every call)
  hipMemsetAsync(deg, 0, (size_t)NN * 4, stream);
  k_deg<<<(NE + 255) / 256, 256, 0, stream>>>(ei, deg);
  k_scan_a<<<NBLK, 256, 0, stream>>>(deg, lps, bsum);
  k_scan_b<<<1, 256, 0, stream>>>(bsum, bpre);
  k_fill<<<NBLK, 256, 0, stream>>>(lps, bpre, rowptr, cursor);
  k_scatter<<<(NE + 255) / 256, 256, 0, stream>>>(ei, cursor, esrc, eidl);

  for (int l = 0; l < NL; ++l) {
    hipMemsetAsync(stats, 0, 2 * D * 4, stream);
    k_aggr<<<3125, 256, 0, stream>>>(h, ea, eW, eb, rowptr, esrc, eidl, eps, l, z);
    k_mlp<<<(NN + 255) / 256, 256, 0, stream>>>(W1t, b1, W2t, b2, l, z);
    k_stats<<<512, 256, 0, stream>>>(z, stats);
    float* ho = (l == NL - 1) ? out : h;
    k_apply<<<1024, 256, 0, stream>>>(z, stats, gamma, beta, l, (l == NL - 1) ? 1 : 0, ho);
  }
}